// Round 7
// baseline (342.305 us; speedup 1.0000x reference)
//
#include <hip/hip_runtime.h>

#define IMG_H 512
#define IMG_W 512
#define NPLANES 24          // N*C = 8*3
#define ROWS_PER_BLK 16     // output rows per block
#define NITER 26            // ROWS_PER_BLK + 10 halo rows
#define NBLOCKS (32 * 24)
#define TOTAL_PIX 6291456.0f // 8*3*512*512

typedef float f32x2 __attribute__((ext_vector_type(2)));
typedef float f32x4 __attribute__((ext_vector_type(4)));

// Gaussian window, sigma=1.5, K=11, normalized (matches jnp reference ~1e-7)
constexpr float GWc[11] = {
    0.00102838f, 0.00759876f, 0.03600050f, 0.10935817f, 0.21300535f,
    0.26601172f, 0.21300535f, 0.10935817f, 0.03600050f, 0.00759876f,
    0.00102838f};

// Round 7 (= round 6 resubmit after infra failure; + 16B LDS alignment fix).
// Measured wall (R0-R5): ~75us invariant, VALU busy only 27-39us. Root
// cause: __syncthreads drains vmcnt(0) (compiler emits s_waitcnt vmcnt(0)
// before s_barrier), so every barrier'd version had depth-0 prefetch ->
// 26 serial load-latency exposures per block. Fix combo:
//  - NO barrier in the row loop: each wave owns a private 76-col LDS strip
//    (same-wave DS ops are in-order; compiler inserts lgkmcnt waits)
//  - depth-3 register prefetch, full 26-slot unroll (i%3, i%11 compile-time)
//    -> counted vmcnt waits with ~2 slots of slack
//  - 1 output col/thread keeps circular buffers at ~55 VGPR (R5's 2-col
//    variant spilled: 256 VGPR, 60MB scratch writes)
//  - lanes 0..37 load col-PAIRS as dwordx2 (2 vector loads/slot/wave);
//    masks precomputed, applied at STAGE time so they don't force an
//    early vmcnt wait at load time
extern "C" __global__ __launch_bounds__(512) void ssim_structure_kernel(
    const float* __restrict__ x, const float* __restrict__ y,
    float* __restrict__ accum, unsigned int* __restrict__ counter,
    float* __restrict__ out) {
  const int tid = threadIdx.x;
  const int lane = tid & 63;
  const int w = tid >> 6;        // wave id 0..7 -> 64-col strip
  const int band = blockIdx.x;   // 0..31
  const int plane = blockIdx.y;  // 0..23

  const size_t pbase = (size_t)plane * IMG_H * IMG_W;
  const float* __restrict__ xp = x + pbase;
  const float* __restrict__ yp = y + pbase;
  const int r0 = band * ROWS_PER_BLK;
  const int cbase = w * 64;      // strip's first output column

  // wave-private double-buffered staging rows: col r (rel, 0..75) holds
  // (x,y) at image col cbase-6+r; pad to 80. 16B-aligned so the paired
  // ds_write_b128 at even indices is legal.
  __shared__ __align__(16) f32x2 lrow[8][2][80];

  // circular register buffers of horizontal sums (1 col/thread)
  f32x2 bm[11];   // (Swx,  Swy)
  f32x2 bq[11];   // (Swxx, Swyy)
  float bxy[11];  // Swxy

  // ---- per-lane load setup: lanes 0..37 each load one col-pair ----
  const int c0 = cbase - 6 + 2 * lane;           // even -> 8B aligned
  const bool ld_active = (lane < 38);            // 38 pairs = 76 cols
  const int cc = min(max(c0, 0), IMG_W - 2);     // clamped pair base
  const float m0 = (c0 >= 0 && c0 < IMG_W) ? 1.f : 0.f;
  const float m1 = (c0 + 1 >= 0 && c0 + 1 < IMG_W) ? 1.f : 0.f;
  const f32x2 mask = {m0, m1};

  // depth-3 prefetch sets (indices compile-time after full unroll)
  f32x2 px[3], py[3];

  float acc = 0.0f;

  auto loadrow = [&](int i, f32x2& vx, f32x2& vy) {
    const int hr = r0 - 5 + i;
    if ((i < NITER) && (hr >= 0) && (hr < IMG_H) && ld_active) {
      const int off = hr * IMG_W + cc;
      vx = *reinterpret_cast<const f32x2*>(xp + off);
      vy = *reinterpret_cast<const f32x2*>(yp + off);
    } else {
      vx = (f32x2){0.f, 0.f};
      vy = (f32x2){0.f, 0.f};
    }
  };

  loadrow(0, px[0], py[0]);
  loadrow(1, px[1], py[1]);
  loadrow(2, px[2], py[2]);

#pragma unroll
  for (int i = 0; i < NITER; ++i) {
    const int s = i % 3;    // compile-time
    const int sel = i & 1;  // compile-time
    const int ii = i % 11;  // compile-time

    // stage row i (loaded 3 slots ago -> counted vmcnt wait, ~2 slots slack)
    if (ld_active) {
      const f32x2 mx = px[s] * mask;
      const f32x2 my = py[s] * mask;
      const f32x4 st = {mx.x, my.x, mx.y, my.y};  // (x,y) pairs, 2 cols
      *reinterpret_cast<f32x4*>(&lrow[w][sel][2 * lane]) = st;
    }

    // issue row i+3 loads immediately (stay in flight across the slot)
    loadrow(i + 3, px[s], py[s]);

    // ---- horizontal pass: 11 overlapping ds_read_b64, window col rel
    // r = lane+1+d for output col cbase+lane (max idx 74 < 80) ----
    {
      f32x2 tm = {0.f, 0.f};
      f32x2 tq = {0.f, 0.f};
      float txy = 0.f;
#pragma unroll
      for (int d = 0; d < 11; ++d) {
        const f32x2 v = lrow[w][sel][lane + 1 + d];
        const float wgt = GWc[d];
        const f32x2 wv = v * wgt;
        tm += wv;
        tq = __builtin_elementwise_fma(wv, v, tq);
        txy = fmaf(wv.x, v.y, txy);
      }
      bm[ii] = tm;
      bq[ii] = tq;
      bxy[ii] = txy;
    }

    // ---- vertical pass + epilogue for output row r0 + (i - 10) ----
    if (i >= 10) {
      f32x2 vm = {0.f, 0.f};
      f32x2 vq = {0.f, 0.f};
      float vxy = 0.f;
#pragma unroll
      for (int k = 0; k < 11; ++k) {
        const int s2 = (ii + 1 + k) % 11;  // compile-time
        const float wgt = GWc[k];
        const f32x2 w2 = {wgt, wgt};
        vm = __builtin_elementwise_fma(bm[s2], w2, vm);
        vq = __builtin_elementwise_fma(bq[s2], w2, vq);
        vxy = fmaf(wgt, bxy[s2], vxy);
      }
      const float sxy = fmaf(-vm.x, vm.y, vxy);
      f32x2 sp = __builtin_elementwise_fma(-vm, vm, vq);
      sp = __builtin_elementwise_max(sp, (f32x2){1e-12f, 1e-12f});
      const float den = sqrtf(sp.x * sp.y) + 1e-4f;
      acc = fmaf(sxy + 1e-4f, __builtin_amdgcn_rcpf(den), acc);
    }
  }

  // ---- block reduction: wave shuffle then cross-wave LDS ----
#pragma unroll
  for (int off = 32; off > 0; off >>= 1) acc += __shfl_down(acc, off, 64);
  __shared__ float wsum[8];
  if (lane == 0) wsum[w] = acc;
  __syncthreads();
  if (tid == 0) {
    float bsum = 0.f;
#pragma unroll
    for (int v = 0; v < 8; ++v) bsum += wsum[v];
    atomicAdd(accum, bsum);
    __threadfence();
    const unsigned int ret = atomicAdd(counter, 1u);
    if (ret == (unsigned int)(NBLOCKS - 1)) {
      // all blocks' accum atomics are fenced-before their counter atomics,
      // so the running total is complete; atomic read bypasses stale caches
      __threadfence();
      const float total = atomicAdd(accum, 0.0f);
      out[0] = 1.0f - total * (1.0f / TOTAL_PIX);
    }
  }
}

extern "C" void kernel_launch(void* const* d_in, const int* in_sizes, int n_in,
                              void* d_out, int out_size, void* d_ws,
                              size_t ws_size, hipStream_t stream) {
  const float* x = (const float*)d_in[0];
  const float* y = (const float*)d_in[1];
  float* out = (float*)d_out;
  float* accum = (float*)d_ws;
  unsigned int* counter = (unsigned int*)((char*)d_ws + sizeof(float));

  hipMemsetAsync(d_ws, 0, 2 * sizeof(float), stream);

  dim3 grid(IMG_H / ROWS_PER_BLK, NPLANES);  // 32 x 24 = 768 blocks
  ssim_structure_kernel<<<grid, 512, 0, stream>>>(x, y, accum, counter, out);
}